// Round 1
// baseline (523.351 us; speedup 1.0000x reference)
//
#include <hip/hip_runtime.h>
#include <hip/hip_bf16.h>

typedef __attribute__((ext_vector_type(4))) float f32x4;
typedef __attribute__((ext_vector_type(8))) short s16x8;

#define NR 512      // rows of x / out
#define KD 512      // inner dim
#define CC 100000   // columns of weight / out
#define BN 32       // cols per block
#define LDSK 40     // padded k-stride in LDS (16B-aligned b128 reads, spread banks)

static __device__ __forceinline__ unsigned short f2bf(float f) {
    union { float f; unsigned u; } v; v.f = f;
    unsigned r = v.u + 0x7FFFu + ((v.u >> 16) & 1u);  // round-to-nearest-even
    return (unsigned short)(r >> 16);
}

// Kernel 1: per-row L2 norm of x + convert x to bf16 (bit pattern in ushort)
__global__ __launch_bounds__(256) void prep_kernel(const float* __restrict__ x,
                                                   float* __restrict__ xn,
                                                   unsigned short* __restrict__ xb) {
    const int row = blockIdx.x;
    const int t = threadIdx.x;
    const float* xr = x + row * KD;
    float v0 = xr[t];
    float v1 = xr[t + 256];
    float ss = v0 * v0 + v1 * v1;
    #pragma unroll
    for (int off = 32; off > 0; off >>= 1) ss += __shfl_down(ss, off, 64);
    __shared__ float sred[4];
    if ((t & 63) == 0) sred[t >> 6] = ss;
    __syncthreads();
    if (t == 0) xn[row] = sqrtf(sred[0] + sred[1] + sred[2] + sred[3]);
    xb[row * KD + t]       = f2bf(v0);
    xb[row * KD + t + 256] = f2bf(v1);
}

// Kernel 2: out[m, c] = clip( (x·w_c) / ||w_c|| / ||x_m||, -1, 1 ) * ||x_m||
// Block: 256 threads (4 waves), 32-col stripe, full M=512, full K=512.
// Wave w computes rows [w*128, w*128+128) x 32 cols via 8x2 mfma_16x16x32 frags.
__global__ __launch_bounds__(256, 3) void gemm_kernel(const float* __restrict__ w,
                                                      const unsigned short* __restrict__ xb,
                                                      const float* __restrict__ xn,
                                                      float* __restrict__ out) {
    __shared__ unsigned short ldsB[BN * LDSK];
    __shared__ float sPart[8][BN];
    __shared__ float sInv[BN];

    const int t    = threadIdx.x;
    const int lane = t & 63;
    const int wv   = t >> 6;          // wave 0..3
    const int c0   = blockIdx.x * BN; // global col base (3125*32 = 100000 exact)
    const int cL   = t & 31;          // staging: local col
    const int kq   = t >> 5;          // staging: k-quad 0..7 (k = kq*4..kq*4+3)

    f32x4 acc[8][2];
    #pragma unroll
    for (int i = 0; i < 8; ++i) {
        acc[i][0] = {0.f, 0.f, 0.f, 0.f};
        acc[i][1] = {0.f, 0.f, 0.f, 0.f};
    }

    float ss = 0.0f;                  // partial sum-of-squares for column cL
    const int rowbase = wv * 128;
    const int arow = lane & 15;       // m within 16-tile  (A: m=lane&15)
    const int akq  = lane >> 4;       // k-quad            (A: k=quad*8+j)

    // prefetch first B tile (kk=0): 4 fp32 per thread, coalesced 128B rows
    const float* wp0 = w + (size_t)(kq * 4) * CC + c0 + cL;
    float bc0 = wp0[0];
    float bc1 = wp0[(size_t)CC];
    float bc2 = wp0[(size_t)2 * CC];
    float bc3 = wp0[(size_t)3 * CC];

    const unsigned short* abase = xb + (rowbase + arow) * KD + akq * 8;

    #pragma unroll 1
    for (int it = 0; it < 16; ++it) {
        const int kk = it * 32;

        // A fragments for this K-slice: direct global (L2-resident x_bf16)
        s16x8 af[8];
        #pragma unroll
        for (int rt = 0; rt < 8; ++rt)
            af[rt] = *(const s16x8*)(abase + rt * 16 * KD + kk);

        // prefetch next B tile (latency hidden behind this iter's MFMAs)
        float bn0 = 0.f, bn1 = 0.f, bn2 = 0.f, bn3 = 0.f;
        if (it < 15) {
            const float* wp = w + (size_t)(kk + 32 + kq * 4) * CC + c0 + cL;
            bn0 = wp[0];
            bn1 = wp[(size_t)CC];
            bn2 = wp[(size_t)2 * CC];
            bn3 = wp[(size_t)3 * CC];
        }

        // column sumsq (fp32, pre-conversion) + pack to bf16
        ss += bc0 * bc0 + bc1 * bc1 + bc2 * bc2 + bc3 * bc3;
        ushort4 pk;
        pk.x = f2bf(bc0);
        pk.y = f2bf(bc1);
        pk.z = f2bf(bc2);
        pk.w = f2bf(bc3);

        __syncthreads();  // prior iter's ds_reads done before overwrite
        *(ushort4*)&ldsB[cL * LDSK + kq * 4] = pk;   // [n][k] transposed, 8B aligned
        __syncthreads();

        // B fragments: n = lane&15 (+16*ct), k = (lane>>4)*8 + j  -> ds_read_b128
        const s16x8 bf0 = *(const s16x8*)&ldsB[(0 * 16 + arow) * LDSK + akq * 8];
        const s16x8 bf1 = *(const s16x8*)&ldsB[(1 * 16 + arow) * LDSK + akq * 8];

        #pragma unroll
        for (int rt = 0; rt < 8; ++rt) {
            acc[rt][0] = __builtin_amdgcn_mfma_f32_16x16x32_bf16(af[rt], bf0, acc[rt][0], 0, 0, 0);
            acc[rt][1] = __builtin_amdgcn_mfma_f32_16x16x32_bf16(af[rt], bf1, acc[rt][1], 0, 0, 0);
        }
        bc0 = bn0; bc1 = bn1; bc2 = bn2; bc3 = bn3;
    }

    // reduce column norms: 8 partials per column
    sPart[kq][cL] = ss;
    __syncthreads();
    if (t < BN) {
        float tot = 0.f;
        #pragma unroll
        for (int i = 0; i < 8; ++i) tot += sPart[i][t];
        sInv[t] = 1.0f / sqrtf(tot);
    }
    __syncthreads();

    // epilogue: C/D layout col=lane&15, row=(lane>>4)*4+reg
    #pragma unroll
    for (int rt = 0; rt < 8; ++rt) {
        const int rbase = rowbase + rt * 16 + akq * 4;
        const f32x4 xnv = *(const f32x4*)(xn + rbase);
        #pragma unroll
        for (int ct = 0; ct < 2; ++ct) {
            const float inv = sInv[ct * 16 + arow];
            float* op = out + (size_t)rbase * CC + c0 + ct * 16 + arow;
            #pragma unroll
            for (int r = 0; r < 4; ++r) {
                float cv = acc[rt][ct][r] * inv / xnv[r];
                cv = fminf(1.0f, fmaxf(-1.0f, cv));
                op[(size_t)r * CC] = cv * xnv[r];
            }
        }
    }
}

// Kernel 3: per-row target fixup (AngleLinear margin term), 512 rows
__global__ __launch_bounds__(512) void fixup_kernel(const int* __restrict__ target,
                                                    const float* __restrict__ xn,
                                                    float* __restrict__ out) {
    const int i = threadIdx.x;
    const int tg = target[i];
    const float xni = xn[i];
    float* p = out + (size_t)i * CC + tg;
    const float val = *p;
    float c = val / xni;
    c = fminf(1.0f, fmaxf(-1.0f, c));
    const float c2 = c * c;
    const float cosm = 8.0f * c2 * c2 - 8.0f * c2 + 1.0f;
    const float theta = acosf(c);
    const float kf = floorf(4.0f * theta / 3.141592653f);
    const float sign = (((int)kf) & 1) ? -1.0f : 1.0f;
    const float phi = sign * cosm - 2.0f * kf;
    const float lam = 1500.0f / 1.1f;  // max(5, 1500/(1+0.1*1))
    const float add = (phi - c) * xni / (1.0f + lam);
    *p = val + add;
}

extern "C" void kernel_launch(void* const* d_in, const int* in_sizes, int n_in,
                              void* d_out, int out_size, void* d_ws, size_t ws_size,
                              hipStream_t stream) {
    const float* x      = (const float*)d_in[0];
    const int*   target = (const int*)d_in[1];
    const float* w      = (const float*)d_in[2];
    float* out = (float*)d_out;

    float* xn = (float*)d_ws;                                        // 512 f32
    unsigned short* xb = (unsigned short*)((char*)d_ws + 2048);      // 512x512 bf16

    prep_kernel<<<NR, 256, 0, stream>>>(x, xn, xb);
    gemm_kernel<<<CC / BN, 256, 0, stream>>>(w, xb, xn, out);
    fixup_kernel<<<1, 512, 0, stream>>>(target, xn, out);
}